// Round 1
// baseline (941.396 us; speedup 1.0000x reference)
//
#include <hip/hip_runtime.h>
#include <math.h>

#define NROWS 8192
#define DD 128
#define EPSV 1.1920929e-07f

__global__ void __launch_bounds__(256)
fused_linattn(const float* __restrict__ x,
              const float* __restrict__ past_mem,
              const float* __restrict__ gamma,
              const float* __restrict__ w_qkv,
              const float* __restrict__ w_forget,
              float* __restrict__ out_retr,
              float* __restrict__ out_mem) {
    const int n = blockIdx.x;
    const int t = threadIdx.x;

    __shared__ __align__(16) float s_xn[DD];
    __shared__ __align__(16) float s_q[DD];
    __shared__ __align__(16) float s_k[DD];
    __shared__ __align__(16) float s_v[DD];
    __shared__ float s_tmp[4];
    __shared__ float4 s_red[256];

    // ---- 1. RMSNorm: load x row, block-reduce sum of squares ----
    float xv = 0.0f;
    if (t < DD) xv = x[(size_t)n * DD + t];
    float ss = xv * xv;
    #pragma unroll
    for (int off = 32; off > 0; off >>= 1) ss += __shfl_down(ss, off, 64);
    if ((t & 63) == 0) s_tmp[t >> 6] = ss;
    __syncthreads();
    const float sumsq = s_tmp[0] + s_tmp[1] + s_tmp[2] + s_tmp[3];
    const float rinv = rsqrtf(sumsq * (1.0f / DD) + EPSV);
    if (t < DD) s_xn[t] = xv * rinv * gamma[t];
    __syncthreads();   // s_xn visible; also orders s_tmp reads above before re-write below

    // ---- 2. forget-gate dot partial (reduction completes after GEMM) ----
    float fp = (t < DD) ? s_xn[t] * w_forget[t] : 0.0f;
    #pragma unroll
    for (int off = 32; off > 0; off >>= 1) fp += __shfl_down(fp, off, 64);
    if ((t & 63) == 0) s_tmp[t >> 6] = fp;

    // ---- 3. QKV projection: thread t -> row t (q|k), row t+256 (v) ----
    const float4* xn4 = (const float4*)s_xn;
    {
        const float4* wrow = (const float4*)(w_qkv + (size_t)t * DD);
        float a = 0.0f;
        #pragma unroll 8
        for (int i = 0; i < DD / 4; ++i) {
            float4 w4 = wrow[i];
            float4 xx = xn4[i];
            a = fmaf(w4.x, xx.x, a);
            a = fmaf(w4.y, xx.y, a);
            a = fmaf(w4.z, xx.z, a);
            a = fmaf(w4.w, xx.w, a);
        }
        const float s = a / (1.0f + expf(-a));   // silu
        if (t < DD) s_q[t] = s;
        else        s_k[t - DD] = s;
    }
    if (t < DD) {
        const float4* wrow = (const float4*)(w_qkv + (size_t)(t + 2 * DD) * DD);
        float a = 0.0f;
        #pragma unroll 8
        for (int i = 0; i < DD / 4; ++i) {
            float4 w4 = wrow[i];
            float4 xx = xn4[i];
            a = fmaf(w4.x, xx.x, a);
            a = fmaf(w4.y, xx.y, a);
            a = fmaf(w4.z, xx.z, a);
            a = fmaf(w4.w, xx.w, a);
        }
        s_v[t] = a;   // v: no activation
    }
    __syncthreads();
    const float fdot = s_tmp[0] + s_tmp[1] + s_tmp[2] + s_tmp[3];
    const float f = 1.0f / (1.0f + expf(-fdot));   // sigmoid

    // ---- 4. memory lerp + retrieval stream ----
    // thread t owns float4-column qc = t&31 (e = 4*qc..), d-group dg = t>>5.
    // Per iteration a full wave touches 1 KiB contiguous: perfectly coalesced.
    const int qc = t & 31;
    const int dg = t >> 5;
    const float4 v4 = ((const float4*)s_v)[qc];
    float4 acc = make_float4(0.0f, 0.0f, 0.0f, 0.0f);
    const size_t base = (size_t)n * (DD * DD);
    const float4* past4 = (const float4*)(past_mem + base);
    float4* mem4 = (float4*)(out_mem + base);
    #pragma unroll 4
    for (int d = dg; d < DD; d += 8) {
        const float kd = s_k[d];
        const float qd = s_q[d];
        float4 p = past4[d * 32 + qc];
        float4 m;
        // mem = past + f*(k*v - past)   (matches jnp lerp order)
        m.x = fmaf(f, fmaf(kd, v4.x, -p.x), p.x);
        m.y = fmaf(f, fmaf(kd, v4.y, -p.y), p.y);
        m.z = fmaf(f, fmaf(kd, v4.z, -p.z), p.z);
        m.w = fmaf(f, fmaf(kd, v4.w, -p.w), p.w);
        mem4[d * 32 + qc] = m;
        acc.x = fmaf(qd, m.x, acc.x);
        acc.y = fmaf(qd, m.y, acc.y);
        acc.z = fmaf(qd, m.z, acc.z);
        acc.w = fmaf(qd, m.w, acc.w);
    }
    s_red[t] = acc;   // t == dg*32 + qc
    __syncthreads();
    if (t < 32) {
        float4 tot = s_red[t];
        #pragma unroll
        for (int g = 1; g < 8; ++g) {
            float4 r = s_red[g * 32 + t];
            tot.x += r.x; tot.y += r.y; tot.z += r.z; tot.w += r.w;
        }
        ((float4*)(out_retr + (size_t)n * DD))[t] = tot;
    }
}

extern "C" void kernel_launch(void* const* d_in, const int* in_sizes, int n_in,
                              void* d_out, int out_size, void* d_ws, size_t ws_size,
                              hipStream_t stream) {
    (void)in_sizes; (void)n_in; (void)out_size; (void)d_ws; (void)ws_size;
    const float* x        = (const float*)d_in[0];
    const float* past_mem = (const float*)d_in[1];
    const float* gamma    = (const float*)d_in[2];
    const float* w_qkv    = (const float*)d_in[3];
    const float* w_forget = (const float*)d_in[4];
    float* out_retr = (float*)d_out;                         // [N, D]   first output
    float* out_mem  = (float*)d_out + (size_t)NROWS * DD;    // [N, D, D] second output

    fused_linattn<<<dim3(NROWS), dim3(256), 0, stream>>>(
        x, past_mem, gamma, w_qkv, w_forget, out_retr, out_mem);
}